// Round 2
// baseline (1337.418 us; speedup 1.0000x reference)
//
#include <hip/hip_runtime.h>

// b=16, s=4096, h=16, p=64, n=64
constexpr int S  = 4096;
constexpr int H  = 16;
constexpr int P  = 64;
constexpr int NN = 64;
constexpr int PAIRS = 256;            // b*h
constexpr int KSPLIT = 4;             // K-split across blocks
constexpr int KCHUNK = S / KSPLIT;    // 1024 t per block
constexpr int KW = KCHUNK / 4;        // 256 t per wave
constexpr int TT = 16;                // t-rows per LDS tile
constexpr int LDW = 68;               // padded LDS row stride (floats), 16B-aligned

// ---------------------------------------------------------------------------
// Kernel 1: inclusive cumsum of A over t, kept in A's own [b][t][h] layout.
// grid = 16 (one block per b), block = 1024 (16 h x 64 segments of 64 t).
// All global loads/stores are h-major => 16 consecutive h = 64B line, coalesced.
// ---------------------------------------------------------------------------
__global__ __launch_bounds__(1024) void scan_cs(const float* __restrict__ A,
                                                float* __restrict__ cs) {
    const int b   = blockIdx.x;
    const int tid = threadIdx.x;
    const int h   = tid & 15;
    const int seg = tid >> 4;              // 0..63, owns t in [seg*64, seg*64+64)
    const float* Ab = A  + (size_t)b * S * H;
    float*       cb = cs + (size_t)b * S * H;
    const int base = seg * 64 * H + h;

    float s = 0.f;
#pragma unroll 8
    for (int i = 0; i < 64; ++i) s += Ab[base + i * H];

    __shared__ float ps[16][65];           // +1 pad: lanes (h-major) hit distinct banks
    ps[h][seg] = s;
    __syncthreads();
    for (int off = 1; off < 64; off <<= 1) {
        float add = (seg >= off) ? ps[h][seg - off] : 0.f;
        __syncthreads();
        ps[h][seg] += add;
        __syncthreads();
    }
    float run = ps[h][seg] - s;            // exclusive prefix for this segment
#pragma unroll 8
    for (int i = 0; i < 64; ++i) {
        run += Ab[base + i * H];
        cb[base + i * H] = run;            // inclusive cumsum; cb[(S-1)*H+h] = total
    }
}

// ---------------------------------------------------------------------------
// Kernel 2: out[pair][p][n] += sum_t exp(tot - cs[t]) * X[t][p] * B[t][n]
// grid = (256 pairs, KSPLIT). Block 256 = 4 waves; each wave owns a private
// 256-t K-range and a private LDS tile => NO barriers in the K-loop.
// Thread tile 8x8 (64 lanes = full 64x64 output per wave), register prefetch.
// ---------------------------------------------------------------------------
__global__ __launch_bounds__(256, 4) void mainK(const float* __restrict__ X,
                                                const float* __restrict__ Bm,
                                                const float* __restrict__ cs,
                                                float* __restrict__ out) {
    const int pair = blockIdx.x;
    const int ks   = blockIdx.y;
    const int b = pair >> 4, h = pair & 15;
    const int tid  = threadIdx.x;
    const int wave = tid >> 6;
    const int lane = tid & 63;

    const float* Xp  = X  + (size_t)b * S * H * P  + (size_t)h * P;   // + t*H*P  + p
    const float* Bp  = Bm + (size_t)b * S * H * NN + (size_t)h * NN;  // + t*H*NN + n
    const float* csb = cs + (size_t)b * S * H + h;                    // + t*H
    const float tot  = csb[(size_t)(S - 1) * H];

    __shared__ float lds[4][2][TT][LDW];   // [wave][X|B][row][col], 34816 B
    float (*Xs)[LDW] = lds[wave][0];
    float (*Bs)[LDW] = lds[wave][1];

    // staging roles: lane -> (row, quad-column)
    const int rowA = lane >> 2;            // 0..15
    const int q    = lane & 3;             // 0..3; float4 cols q, q+4, q+8, q+12
    // compute roles: lane -> 8x8 tile at (p0, n0)
    const int p0 = (lane >> 3) * 8;
    const int n0 = (lane & 7) * 8;

    float acc[8][8];
#pragma unroll
    for (int i = 0; i < 8; ++i)
#pragma unroll
        for (int j = 0; j < 8; ++j) acc[i][j] = 0.f;

    const int tw0 = ks * KCHUNK + wave * KW;

    float4 xr[4], br[4];
    float wv;
    {   // prefetch tile 0
        const int t = tw0 + rowA;
        wv = __expf(tot - csb[(size_t)t * H]);
        const float* xrow = Xp + (size_t)t * (H * P);
        const float* brow = Bp + (size_t)t * (H * NN);
#pragma unroll
        for (int i = 0; i < 4; ++i) {
            xr[i] = *(const float4*)(xrow + (size_t)(q + 4 * i) * 4);
            br[i] = *(const float4*)(brow + (size_t)(q + 4 * i) * 4);
        }
    }

    for (int tile = 0; tile < KW / TT; ++tile) {
        // commit prefetched tile to this wave's private LDS region (X pre-scaled)
#pragma unroll
        for (int i = 0; i < 4; ++i) {
            float4 xs = make_float4(xr[i].x * wv, xr[i].y * wv, xr[i].z * wv, xr[i].w * wv);
            *(float4*)&Xs[rowA][(q + 4 * i) * 4] = xs;
            *(float4*)&Bs[rowA][(q + 4 * i) * 4] = br[i];
        }
        // prefetch next tile from global (overlaps compute below)
        if (tile + 1 < KW / TT) {
            const int t = tw0 + (tile + 1) * TT + rowA;
            wv = __expf(tot - csb[(size_t)t * H]);
            const float* xrow = Xp + (size_t)t * (H * P);
            const float* brow = Bp + (size_t)t * (H * NN);
#pragma unroll
            for (int i = 0; i < 4; ++i) {
                xr[i] = *(const float4*)(xrow + (size_t)(q + 4 * i) * 4);
                br[i] = *(const float4*)(brow + (size_t)(q + 4 * i) * 4);
            }
        }
        // 16 rows x 8x8 outer product from LDS (per-wave in-order LDS pipe:
        // reads correctly wait on this wave's own ds_writes; no barrier needed)
#pragma unroll
        for (int r = 0; r < TT; ++r) {
            const float4 x0 = *(const float4*)&Xs[r][p0];
            const float4 x1 = *(const float4*)&Xs[r][p0 + 4];
            const float4 b0 = *(const float4*)&Bs[r][n0];
            const float4 b1 = *(const float4*)&Bs[r][n0 + 4];
            const float xa[8] = {x0.x, x0.y, x0.z, x0.w, x1.x, x1.y, x1.z, x1.w};
            const float ba[8] = {b0.x, b0.y, b0.z, b0.w, b1.x, b1.y, b1.z, b1.w};
#pragma unroll
            for (int i = 0; i < 8; ++i)
#pragma unroll
                for (int j = 0; j < 8; ++j)
                    acc[i][j] = fmaf(xa[i], ba[j], acc[i][j]);
        }
    }

    // cross-wave reduction in LDS (reuse tile memory), then coalesced atomics
    float* red = &lds[0][0][0][0];         // 64*64 = 16 KB < 34816 B
    __syncthreads();
    for (int wv_ = 0; wv_ < 4; ++wv_) {
        if (wave == wv_) {
#pragma unroll
            for (int i = 0; i < 8; ++i) {
#pragma unroll
                for (int j4 = 0; j4 < 2; ++j4) {
                    float* dst = &red[(size_t)(p0 + i) * NN + n0 + j4 * 4];
                    float4 v = make_float4(acc[i][j4*4+0], acc[i][j4*4+1],
                                           acc[i][j4*4+2], acc[i][j4*4+3]);
                    if (wv_ == 0) {
                        *(float4*)dst = v;
                    } else {
                        float4 old = *(const float4*)dst;
                        *(float4*)dst = make_float4(old.x+v.x, old.y+v.y, old.z+v.z, old.w+v.w);
                    }
                }
            }
        }
        __syncthreads();
    }

    float* op = out + (size_t)pair * (P * NN);
#pragma unroll
    for (int k = 0; k < 16; ++k) {
        const int e = tid + k * 256;       // coalesced
        atomicAdd(&op[e], red[e]);
    }
}

extern "C" void kernel_launch(void* const* d_in, const int* in_sizes, int n_in,
                              void* d_out, int out_size, void* d_ws, size_t ws_size,
                              hipStream_t stream) {
    const float* X = (const float*)d_in[0];
    const float* A = (const float*)d_in[1];
    const float* B = (const float*)d_in[2];
    // d_in[3] = C is dead in the reference (computed then discarded)
    float* out = (float*)d_out;
    float* cs  = (float*)d_ws;             // 16*4096*16 floats = 4 MiB

    hipMemsetAsync(d_out, 0, (size_t)out_size * sizeof(float), stream);
    scan_cs<<<16, 1024, 0, stream>>>(A, cs);
    mainK<<<dim3(PAIRS, KSPLIT), 256, 0, stream>>>(X, B, cs, out);
}